// Round 1
// baseline (248.078 us; speedup 1.0000x reference)
//
#include <hip/hip_runtime.h>
#include <stdint.h>

typedef __attribute__((ext_vector_type(4))) float  float4v;
typedef __attribute__((ext_vector_type(8))) __bf16 bf16x8;
typedef __attribute__((ext_vector_type(8))) unsigned short ushort8;
typedef __attribute__((ext_vector_type(4))) unsigned short ushort4v;

#define B_DIM 8192
#define H_DIM 1024
#define O_DIM 1024

static __device__ __forceinline__ unsigned short f32_to_bf16(float f) {
  union { float f; unsigned int u; } v; v.f = f;
  unsigned int u = v.u;
  unsigned int r = u + 0x7FFFu + ((u >> 16) & 1u);  // round-to-nearest-even
  return (unsigned short)(r >> 16);
}

// ---------------------------------------------------------------------------
// coeff[m][b]: m=0..3 -> mix*softmax_m ; m=4 -> (1-mix)
// ---------------------------------------------------------------------------
__global__ void prep_coeff(const float* __restrict__ se, const float* __restrict__ curv,
                           const float* __restrict__ gw, const float* __restrict__ gb,
                           float* __restrict__ cfg) {
  int b = blockIdx.x * blockDim.x + threadIdx.x;
  if (b >= B_DIM) return;
  float s = se[b];
  float l0 = s * gw[0] + gb[0];
  float l1 = s * gw[1] + gb[1];
  float l2 = s * gw[2] + gb[2];
  float l3 = s * gw[3] + gb[3];
  float mx = fmaxf(fmaxf(l0, l1), fmaxf(l2, l3));
  float e0 = __expf(l0 - mx), e1 = __expf(l1 - mx), e2 = __expf(l2 - mx), e3 = __expf(l3 - mx);
  float mix = 1.0f / (1.0f + __expf(-curv[b]));
  float inv = mix / (e0 + e1 + e2 + e3);
  cfg[0 * B_DIM + b] = e0 * inv;
  cfg[1 * B_DIM + b] = e1 * inv;
  cfg[2 * B_DIM + b] = e2 * inv;
  cfg[3 * B_DIM + b] = e3 * inv;
  cfg[4 * B_DIM + b] = 1.0f - mix;
}

// ---------------------------------------------------------------------------
// state fp32 [B][H] -> bf16 [B][H]
// ---------------------------------------------------------------------------
__global__ void cast_state(const float* __restrict__ src, unsigned short* __restrict__ dst, int n4) {
  int i = blockIdx.x * blockDim.x + threadIdx.x;
  if (i >= n4) return;
  float4v v = ((const float4v*)src)[i];
  ushort4v o;
  o.x = f32_to_bf16(v.x); o.y = f32_to_bf16(v.y);
  o.z = f32_to_bf16(v.z); o.w = f32_to_bf16(v.w);
  ((ushort4v*)dst)[i] = o;
}

// ---------------------------------------------------------------------------
// basis [4][H][O] + prj_w [H][O]  ->  Wt bf16 [5][O][H]   (LDS-tiled transpose)
// grid: (O/64, H/64, 5), block 256
// ---------------------------------------------------------------------------
__global__ void transpose_cast(const float* __restrict__ basis, const float* __restrict__ prjw,
                               unsigned short* __restrict__ Wt) {
  __shared__ __align__(16) unsigned short t[64 * 72];  // pad 8 shorts/row
  int m = blockIdx.z;
  const float* src = (m < 4) ? (basis + (size_t)m * H_DIM * O_DIM) : prjw;  // [H][O]
  int o0 = blockIdx.x * 64, h0 = blockIdx.y * 64;
  int tid = threadIdx.x;
  int r  = tid >> 4;          // 0..15
  int c4 = (tid & 15) * 4;    // 0..60
#pragma unroll
  for (int p = 0; p < 4; ++p) {
    int h = r + p * 16;
    float4v v = *(const float4v*)(src + (size_t)(h0 + h) * O_DIM + o0 + c4);
    t[(c4 + 0) * 72 + h] = f32_to_bf16(v.x);
    t[(c4 + 1) * 72 + h] = f32_to_bf16(v.y);
    t[(c4 + 2) * 72 + h] = f32_to_bf16(v.z);
    t[(c4 + 3) * 72 + h] = f32_to_bf16(v.w);
  }
  __syncthreads();
#pragma unroll
  for (int i = 0; i < 2; ++i) {
    int C = i * 256 + tid;        // 0..511 : 64 rows x 8 chunks
    int o = C >> 3, cc = C & 7;
    ushort8 val = *(const ushort8*)(t + o * 72 + cc * 8);
    *(ushort8*)(Wt + ((size_t)m * O_DIM + o0 + o) * H_DIM + h0 + cc * 8) = val;
  }
}

// ---------------------------------------------------------------------------
// Fused 5-mode GEMM + combine.
//  A  bf16 [B][H] ; Wt bf16 [5][O][H] ; cfg [5][B] ; out fp32 [B][O]
//  block tile 128x128, 4 waves of 64x64 (4x4 of 16x16x32 mfma), BK=64.
//  global_load_lds(16B) staging; XOR swizzle (chunk ^= row&7) applied on the
//  global-fetch side so frag ds_read_b128s are bank-conflict-free.
// ---------------------------------------------------------------------------
__global__ __launch_bounds__(256, 2)
void gemm_fused(const unsigned short* __restrict__ A,
                const unsigned short* __restrict__ Wt,
                const float* __restrict__ cfg,
                const float* __restrict__ prjb,
                float* __restrict__ out) {
  __shared__ __align__(16) unsigned short sA[128 * 64];
  __shared__ __align__(16) unsigned short sB[128 * 64];
  __shared__ __align__(16) float scf[5 * 128];

  const int tid  = threadIdx.x;
  const int lane = tid & 63;
  const int wave = tid >> 6;
  const int row0 = blockIdx.x * 128;
  const int col0 = blockIdx.y * 128;
  const int wrow = (wave >> 1) * 64;
  const int wcol = (wave & 1) * 64;
  const int q  = lane >> 4;   // quad 0..3
  const int ln = lane & 15;

  for (int i = tid; i < 5 * 128; i += 256)
    scf[i] = cfg[(i >> 7) * B_DIM + row0 + (i & 127)];

  // staging pattern: issue j covers LDS chunks L=(wave*4+j)*64+lane (16B each);
  // chunk L holds (row=L>>3, global chunk c=(L&7)^(row&7))
  int srow[4], scol[4];
#pragma unroll
  for (int j = 0; j < 4; ++j) {
    int L = (wave * 4 + j) * 64 + lane;
    srow[j] = L >> 3;
    scol[j] = (L & 7) ^ (srow[j] & 7);
  }

  float4v acc[4][4];
  float4v oacc[4][4];
#pragma unroll
  for (int i = 0; i < 4; ++i)
#pragma unroll
    for (int j = 0; j < 4; ++j)
      oacc[i][j] = (float4v){0.f, 0.f, 0.f, 0.f};

  for (int mode = 0; mode < 5; ++mode) {
#pragma unroll
    for (int i = 0; i < 4; ++i)
#pragma unroll
      for (int j = 0; j < 4; ++j)
        acc[i][j] = (float4v){0.f, 0.f, 0.f, 0.f};

    const unsigned short* Wm = Wt + (size_t)mode * O_DIM * H_DIM;

    for (int kt = 0; kt < 16; ++kt) {
      const int k0 = kt * 64;
      __syncthreads();  // previous compute done before LDS overwrite
#pragma unroll
      for (int j = 0; j < 4; ++j) {
        const unsigned short* ga = A  + (size_t)(row0 + srow[j]) * H_DIM + k0 + scol[j] * 8;
        const unsigned short* gw = Wm + (size_t)(col0 + srow[j]) * H_DIM + k0 + scol[j] * 8;
        unsigned short* la = sA + (wave * 4 + j) * 512;  // wave-uniform LDS base
        unsigned short* lb = sB + (wave * 4 + j) * 512;
        __builtin_amdgcn_global_load_lds(
            (const __attribute__((address_space(1))) void*)ga,
            (__attribute__((address_space(3))) void*)la, 16, 0, 0);
        __builtin_amdgcn_global_load_lds(
            (const __attribute__((address_space(1))) void*)gw,
            (__attribute__((address_space(3))) void*)lb, 16, 0, 0);
      }
      __syncthreads();  // vmcnt(0) drain + barrier

#pragma unroll
      for (int kk = 0; kk < 2; ++kk) {
        bf16x8 af[4], bfr[4];
#pragma unroll
        for (int t = 0; t < 4; ++t) {
          int ra = wrow + t * 16 + ln;
          int ca = (kk * 4 + q) ^ (ra & 7);
          af[t] = *(const bf16x8*)(sA + ra * 64 + ca * 8);
          int rb = wcol + t * 16 + ln;
          int cb = (kk * 4 + q) ^ (rb & 7);
          bfr[t] = *(const bf16x8*)(sB + rb * 64 + cb * 8);
        }
#pragma unroll
        for (int ti = 0; ti < 4; ++ti)
#pragma unroll
          for (int tj = 0; tj < 4; ++tj)
            acc[ti][tj] = __builtin_amdgcn_mfma_f32_16x16x32_bf16(
                af[ti], bfr[tj], acc[ti][tj], 0, 0, 0);
      }
    }

    // oacc += coeff[mode][row] * acc   (C/D layout: row = q*4 + reg, col = ln)
#pragma unroll
    for (int ti = 0; ti < 4; ++ti) {
      int rl = wrow + ti * 16 + q * 4;
      float4v c4 = *(const float4v*)(scf + mode * 128 + rl);
#pragma unroll
      for (int tj = 0; tj < 4; ++tj)
        oacc[ti][tj] += c4 * acc[ti][tj];
    }
  }

  // epilogue: + (1-mix)*prj_b , store
#pragma unroll
  for (int ti = 0; ti < 4; ++ti) {
    int rl = wrow + ti * 16 + q * 4;
    float4v cb = *(const float4v*)(scf + 4 * 128 + rl);
#pragma unroll
    for (int tj = 0; tj < 4; ++tj) {
      int col = col0 + wcol + tj * 16 + ln;
      float pb = prjb[col];
      float4v v = oacc[ti][tj] + cb * pb;
      size_t base = (size_t)(row0 + rl) * O_DIM + col;
      out[base]             = v.x;
      out[base + O_DIM]     = v.y;
      out[base + 2 * O_DIM] = v.z;
      out[base + 3 * O_DIM] = v.w;
    }
  }
}

// ---------------------------------------------------------------------------
extern "C" void kernel_launch(void* const* d_in, const int* in_sizes, int n_in,
                              void* d_out, int out_size, void* d_ws, size_t ws_size,
                              hipStream_t stream) {
  const float* state = (const float*)d_in[0];
  const float* se    = (const float*)d_in[1];
  const float* curv  = (const float*)d_in[2];
  const float* basis = (const float*)d_in[3];
  const float* gw    = (const float*)d_in[4];
  const float* gb    = (const float*)d_in[5];
  const float* prjw  = (const float*)d_in[6];
  const float* prjb  = (const float*)d_in[7];
  float* out = (float*)d_out;

  char* ws = (char*)d_ws;
  unsigned short* Abf = (unsigned short*)ws;                               // 16 MB
  unsigned short* Wt  = (unsigned short*)(ws + (size_t)16 * 1024 * 1024);  // 10 MB
  float* cfg          = (float*)(ws + (size_t)28 * 1024 * 1024);           // 160 KB

  prep_coeff<<<B_DIM / 256, 256, 0, stream>>>(se, curv, gw, gb, cfg);
  cast_state<<<(B_DIM * H_DIM / 4) / 256, 256, 0, stream>>>(state, Abf, B_DIM * H_DIM / 4);
  dim3 tg(O_DIM / 64, H_DIM / 64, 5);
  transpose_cast<<<tg, 256, 0, stream>>>(basis, prjw, Wt);
  dim3 gg(B_DIM / 128, O_DIM / 128);
  gemm_fused<<<gg, 256, 0, stream>>>(Abf, Wt, cfg, prjb, out);
}